// Round 7
// baseline (225.601 us; speedup 1.0000x reference)
//
#include <hip/hip_runtime.h>
#include <hip/hip_bf16.h>

// B=2, T=2048, D=1024, H=16, dh=64. f32 in/out, bf16 MFMA internally.
// R7: attention reads K/V MFMA fragments DIRECTLY from global (L2-resident;
// R6's FETCH=12MB proved it). No K/V LDS, no barriers, no staging chain.
// LDS = per-wave P only. GEMMs unchanged (m97 structure).

typedef __attribute__((ext_vector_type(8))) short bf16x8;
typedef __attribute__((ext_vector_type(4))) float f32x4;

__device__ __forceinline__ ushort f2bf(float f) {
  unsigned u = __builtin_bit_cast(unsigned, f);
  unsigned r = (u + 0x7fffu + ((u >> 16) & 1u)) >> 16;   // RNE
  return (ushort)r;
}

__device__ __forceinline__ void gload16(const ushort* g, ushort* l) {
  auto gp = (const __attribute__((address_space(1))) void*)g;
  auto lp = (__attribute__((address_space(3))) void*)l;
  __builtin_amdgcn_global_load_lds(gp, lp, 16, 0, 0);  // lane i -> base + i*16B
}

// ---------------- convert x: f32 -> bf16 ----------------
__global__ __launch_bounds__(256) void cvt_f32_bf16(const float* __restrict__ in,
                                                    ushort* __restrict__ out, int n) {
  int i = (blockIdx.x * 256 + threadIdx.x) * 4;
  int stride = gridDim.x * 256 * 4;
  for (; i < n; i += stride) {
    float4 v = *(const float4*)(in + i);
    ushort4 o = { f2bf(v.x), f2bf(v.y), f2bf(v.z), f2bf(v.w) };
    *(ushort4*)(out + i) = o;
  }
}

// ---------------- transpose+convert: in[R][C] f32 -> out[C][R] bf16 ----------------
__global__ __launch_bounds__(256) void tcvt(const float* __restrict__ in,
                                            ushort* __restrict__ out, int R, int C) {
  __shared__ float tile[32][33];
  int c0 = blockIdx.x * 32, r0 = blockIdx.y * 32;
  int tx = threadIdx.x, ty = threadIdx.y;  // (32, 8)
  #pragma unroll
  for (int i = 0; i < 32; i += 8) tile[ty + i][tx] = in[(size_t)(r0 + ty + i) * C + c0 + tx];
  __syncthreads();
  #pragma unroll
  for (int i = 0; i < 32; i += 8) out[(size_t)(c0 + ty + i) * R + r0 + tx] = f2bf(tile[tx][ty + i]);
}

// ---------------- bf16 transpose: in [32][2048][64] -> out [32][64][2048] ----------------
__global__ __launch_bounds__(256) void vtrans(const ushort* __restrict__ in,
                                              ushort* __restrict__ out) {
  __shared__ ushort tile[32][33];
  int t0 = blockIdx.x * 32, d0 = blockIdx.y * 32, bh = blockIdx.z;
  int tx = threadIdx.x, ty = threadIdx.y;  // (32, 8)
  const ushort* src = in + (size_t)bh * 2048 * 64;
  ushort* dst = out + (size_t)bh * 64 * 2048;
  #pragma unroll
  for (int i = 0; i < 32; i += 8) tile[ty + i][tx] = src[(size_t)(t0 + ty + i) * 64 + d0 + tx];
  __syncthreads();
  #pragma unroll
  for (int i = 0; i < 32; i += 8) dst[(size_t)(d0 + ty + i) * 2048 + t0 + tx] = tile[tx][ty + i];
}

// ---------------- bf16 GEMM (m97 structure): C[M,N] = A[M,K] * BT[N,K]^T ----------------
// EPI=0: scatter bf16 into q/k/v [bh][t][64] (contiguous).  EPI=1: f32 store.
template <int EPI>
__global__ __launch_bounds__(256) void gemm_bf16(const ushort* __restrict__ A,
                                                 const ushort* __restrict__ BT,
                                                 ushort* __restrict__ qo, ushort* __restrict__ ko,
                                                 ushort* __restrict__ vo, float* __restrict__ outf,
                                                 int M, int N, int K) {
  __shared__ ushort Als[128 * 32];
  __shared__ ushort Bls[128 * 32];
  const int tid = threadIdx.x;
  const int lane = tid & 63;
  const int w = tid >> 6;
  const int wr = w >> 1, wc = w & 1;
  const int fr = lane & 15, fq = lane >> 4;
  const int bm0 = blockIdx.y * 128, bn0 = blockIdx.x * 128;
  const int srow = lane >> 2;
  const int scol = (lane & 3) * 8;

  f32x4 acc[4][4];
  #pragma unroll
  for (int m = 0; m < 4; m++)
    #pragma unroll
    for (int n = 0; n < 4; n++) acc[m][n] = (f32x4){0.f, 0.f, 0.f, 0.f};

  for (int k0 = 0; k0 < K; k0 += 32) {
    __syncthreads();
    #pragma unroll
    for (int c = 0; c < 2; c++) {
      int chunk = w * 2 + c;
      int rr = chunk * 16 + srow;
      gload16(&A[(size_t)(bm0 + rr) * K + k0 + scol], &Als[chunk * 512]);
      gload16(&BT[(size_t)(bn0 + rr) * K + k0 + scol], &Bls[chunk * 512]);
    }
    __syncthreads();
    bf16x8 a[4], b[4];
    #pragma unroll
    for (int m = 0; m < 4; m++) a[m] = *(bf16x8*)&Als[(wr * 64 + m * 16 + fr) * 32 + fq * 8];
    #pragma unroll
    for (int n = 0; n < 4; n++) b[n] = *(bf16x8*)&Bls[(wc * 64 + n * 16 + fr) * 32 + fq * 8];
    __builtin_amdgcn_s_setprio(1);
    #pragma unroll
    for (int m = 0; m < 4; m++)
      #pragma unroll
      for (int n = 0; n < 4; n++)
        acc[m][n] = __builtin_amdgcn_mfma_f32_16x16x32_bf16(a[m], b[n], acc[m][n], 0, 0, 0);
    __builtin_amdgcn_s_setprio(0);
  }

  #pragma unroll
  for (int m = 0; m < 4; m++) {
    #pragma unroll
    for (int n = 0; n < 4; n++) {
      #pragma unroll
      for (int jj = 0; jj < 4; jj++) {
        int r = bm0 + wr * 64 + m * 16 + fq * 4 + jj;  // C row = 4*(lane>>4)+reg
        int c = bn0 + wc * 64 + n * 16 + fr;           // C col = lane&15
        float val = acc[m][n][jj];
        if (EPI == 0) {
          int which = c >> 10, h = (c >> 6) & 15, dd = c & 63;
          int b_ = r >> 11, t = r & 2047;
          size_t bh = (size_t)(b_ * 16 + h);
          ushort* dst = (which == 0) ? qo : (which == 1 ? ko : vo);
          dst[(bh * 2048 + t) * 64 + dd] = f2bf(val);
        } else {
          outf[(size_t)r * N + c] = val;
        }
      }
    }
  }
}

// ---------------- flash attention (causal), direct-from-L2 fragments ----------------
// grid 1024: bh = bx&31, qt = 31-(bx>>5) (long blocks first). 4 waves/block;
// wave w owns q-rows [w*16, w*16+16). K and V^T fragments are loaded DIRECTLY
// from global per MFMA (L2-resident working set); LDS holds only per-wave P.
// Zero barriers; zero K/V staging.
__global__ __launch_bounds__(256) void attn_fwd(const ushort* __restrict__ qg,
                                                const ushort* __restrict__ kg,
                                                const ushort* __restrict__ vtg,
                                                ushort* __restrict__ y) {
  __shared__ ushort Pw[4][16 * 68];   // per-wave [q 16][kv 64] stride 68

  const int qt = 31 - (int)(blockIdx.x >> 5);
  const int bh = blockIdx.x & 31;
  const int lane = threadIdx.x & 63, w = threadIdx.x >> 6;
  const int fr = lane & 15, fq = lane >> 4;
  const size_t base = (size_t)bh * 2048 * 64;
  const int b_ = bh >> 4, h = bh & 15;
  ushort* P_ = Pw[w];

  // per-lane fragment base pointers
  const ushort* kf = kg + base + (size_t)fr * 64 + fq * 8;     // + (kv0+n*16)*64 + ks*32
  const ushort* vf = vtg + base + (size_t)fr * 2048 + fq * 8;  // + n2*16*2048 + kv0 + ks*32

  // Q fragments direct from global (rows w*16+fr)
  bf16x8 qf0 = *(const bf16x8*)&qg[base + (size_t)(qt * 64 + w * 16 + fr) * 64 + fq * 8];
  bf16x8 qf1 = *(const bf16x8*)&qg[base + (size_t)(qt * 64 + w * 16 + fr) * 64 + 32 + fq * 8];

  f32x4 o0 = {0.f,0.f,0.f,0.f}, o1 = {0.f,0.f,0.f,0.f}, o2 = {0.f,0.f,0.f,0.f}, o3 = {0.f,0.f,0.f,0.f};
  float l0 = 0.f, l1 = 0.f, l2 = 0.f, l3 = 0.f;

  const float C_EXP2 = 0.18033688011112042f;  // 0.125 * log2(e)
  const int rowlim = w * 16 + fq * 4;         // + j = this thread's q-row (in-tile)

  for (int t = 0; t <= qt; ++t) {
    const int kv0 = t * 64;

    // S = Q K^T  [16 x 64] — K frags straight from L2
    f32x4 s0 = {0.f,0.f,0.f,0.f}, s1 = {0.f,0.f,0.f,0.f}, s2 = {0.f,0.f,0.f,0.f}, s3 = {0.f,0.f,0.f,0.f};
    {
      const ushort* kt = kf + (size_t)kv0 * 64;
      #pragma unroll
      for (int ks = 0; ks < 2; ks++) {
        bf16x8 aq = ks ? qf1 : qf0;
        bf16x8 k0v = *(const bf16x8*)(kt + ks * 32);
        bf16x8 k1v = *(const bf16x8*)(kt + 16 * 64 + ks * 32);
        bf16x8 k2v = *(const bf16x8*)(kt + 32 * 64 + ks * 32);
        bf16x8 k3v = *(const bf16x8*)(kt + 48 * 64 + ks * 32);
        s0 = __builtin_amdgcn_mfma_f32_16x16x32_bf16(aq, k0v, s0, 0, 0, 0);
        s1 = __builtin_amdgcn_mfma_f32_16x16x32_bf16(aq, k1v, s1, 0, 0, 0);
        s2 = __builtin_amdgcn_mfma_f32_16x16x32_bf16(aq, k2v, s2, 0, 0, 0);
        s3 = __builtin_amdgcn_mfma_f32_16x16x32_bf16(aq, k3v, s3, 0, 0, 0);
      }
    }

    // no-max softmax in exp2 domain; P -> per-wave LDS
    const bool diag = (t == qt);
    #pragma unroll
    for (int j = 0; j < 4; j++) {
      float v0 = s0[j] * C_EXP2, v1 = s1[j] * C_EXP2, v2 = s2[j] * C_EXP2, v3 = s3[j] * C_EXP2;
      if (diag) {
        int lim = rowlim + j;
        if ( 0 + fr > lim) v0 = -1e30f;
        if (16 + fr > lim) v1 = -1e30f;
        if (32 + fr > lim) v2 = -1e30f;
        if (48 + fr > lim) v3 = -1e30f;
      }
      float p0 = __builtin_amdgcn_exp2f(v0), p1 = __builtin_amdgcn_exp2f(v1);
      float p2 = __builtin_amdgcn_exp2f(v2), p3 = __builtin_amdgcn_exp2f(v3);
      float rs = (p0 + p1) + (p2 + p3);
      P_[(fq * 4 + j) * 68 +  0 + fr] = f2bf(p0);
      P_[(fq * 4 + j) * 68 + 16 + fr] = f2bf(p1);
      P_[(fq * 4 + j) * 68 + 32 + fr] = f2bf(p2);
      P_[(fq * 4 + j) * 68 + 48 + fr] = f2bf(p3);
      if (j == 0) l0 += rs; else if (j == 1) l1 += rs; else if (j == 2) l2 += rs; else l3 += rs;
    }

    // O += P V — V^T frags straight from L2 (in-wave lgkmcnt orders P write->read)
    {
      const ushort* vt = vf + kv0;
      #pragma unroll
      for (int ks = 0; ks < 2; ks++) {
        bf16x8 pa = *(bf16x8*)&P_[fr * 68 + ks * 32 + fq * 8];
        bf16x8 v0v = *(const bf16x8*)(vt + ks * 32);
        bf16x8 v1v = *(const bf16x8*)(vt + (size_t)16 * 2048 + ks * 32);
        bf16x8 v2v = *(const bf16x8*)(vt + (size_t)32 * 2048 + ks * 32);
        bf16x8 v3v = *(const bf16x8*)(vt + (size_t)48 * 2048 + ks * 32);
        o0 = __builtin_amdgcn_mfma_f32_16x16x32_bf16(pa, v0v, o0, 0, 0, 0);
        o1 = __builtin_amdgcn_mfma_f32_16x16x32_bf16(pa, v1v, o1, 0, 0, 0);
        o2 = __builtin_amdgcn_mfma_f32_16x16x32_bf16(pa, v2v, o2, 0, 0, 0);
        o3 = __builtin_amdgcn_mfma_f32_16x16x32_bf16(pa, v3v, o3, 0, 0, 0);
      }
    }
  }

  // cross-lane l reduction over the fr group (sum is linear; done once)
  float l_[4] = {l0, l1, l2, l3};
  #pragma unroll
  for (int j = 0; j < 4; j++) {
    float rs = l_[j];
    rs += __shfl_xor(rs, 1);
    rs += __shfl_xor(rs, 2);
    rs += __shfl_xor(rs, 4);
    rs += __shfl_xor(rs, 8);
    l_[j] = rs;
  }

  f32x4 oo[4] = {o0, o1, o2, o3};
  #pragma unroll
  for (int n2 = 0; n2 < 4; n2++) {
    #pragma unroll
    for (int j = 0; j < 4; j++) {
      int qrow = qt * 64 + w * 16 + fq * 4 + j;
      int dcol = n2 * 16 + fr;
      y[((size_t)(b_ * 2048 + qrow)) * 1024 + h * 64 + dcol] = f2bf(oo[n2][j] / l_[j]);
    }
  }
}

extern "C" void kernel_launch(void* const* d_in, const int* in_sizes, int n_in,
                              void* d_out, int out_size, void* d_ws, size_t ws_size,
                              hipStream_t stream) {
  const float* x = (const float*)d_in[0];
  const float* wqkv = (const float*)d_in[1];
  const float* wproj = (const float*)d_in[2];
  float* out = (float*)d_out;

  ushort* ws = (ushort*)d_ws;
  ushort* xb = ws;                               // 4096*1024
  ushort* wqkvT = xb + 4096 * 1024;              // 3072*1024  [N][K]
  ushort* wprojT = wqkvT + 3072 * 1024;          // 1024*1024  [N][K]
  ushort* qb = wprojT + 1024 * 1024;             // [bh][t][64]
  ushort* kb = qb + 32 * 2048 * 64;              // [bh][t][64]
  ushort* vb = kb + 32 * 2048 * 64;              // [bh][t][64]
  ushort* vtb = vb + 32 * 2048 * 64;             // [bh][64][t]
  ushort* yb = vtb + 32 * 2048 * 64;             // [B,T,1024]

  cvt_f32_bf16<<<1024, 256, 0, stream>>>(x, xb, 4096 * 1024);
  tcvt<<<dim3(96, 32), dim3(32, 8), 0, stream>>>(wqkv, wqkvT, 1024, 3072);
  tcvt<<<dim3(32, 32), dim3(32, 8), 0, stream>>>(wproj, wprojT, 1024, 1024);

  gemm_bf16<0><<<dim3(24, 32), 256, 0, stream>>>(xb, wqkvT, qb, kb, vb, nullptr, 4096, 3072, 1024);
  vtrans<<<dim3(64, 2, 32), dim3(32, 8), 0, stream>>>(vb, vtb);
  attn_fwd<<<1024, 256, 0, stream>>>(qb, kb, vtb, yb);
  gemm_bf16<1><<<dim3(8, 32), 256, 0, stream>>>(yb, wprojT, nullptr, nullptr, nullptr, out, 4096, 1024, 1024);
}

// Round 8
// 191.037 us; speedup vs baseline: 1.1809x; 1.1809x over previous
//
#include <hip/hip_runtime.h>
#include <hip/hip_bf16.h>

// B=2, T=2048, D=1024, H=16, dh=64. f32 in/out, bf16 MFMA internally.
// R8: attn = shared double-buffered K/V LDS staging + named-reg prefetch,
// ONE barrier per KV tile. (Ledger: R2 shared/no-prefetch 98us; R6 private 146;
// R7 no-LDS L2-BW-bound 149. This is the missing quadrant.)

typedef __attribute__((ext_vector_type(8))) short bf16x8;
typedef __attribute__((ext_vector_type(4))) float f32x4;

__device__ __forceinline__ ushort f2bf(float f) {
  unsigned u = __builtin_bit_cast(unsigned, f);
  unsigned r = (u + 0x7fffu + ((u >> 16) & 1u)) >> 16;   // RNE
  return (ushort)r;
}

__device__ __forceinline__ void gload16(const ushort* g, ushort* l) {
  auto gp = (const __attribute__((address_space(1))) void*)g;
  auto lp = (__attribute__((address_space(3))) void*)l;
  __builtin_amdgcn_global_load_lds(gp, lp, 16, 0, 0);  // lane i -> base + i*16B
}

// ---------------- convert x: f32 -> bf16 ----------------
__global__ __launch_bounds__(256) void cvt_f32_bf16(const float* __restrict__ in,
                                                    ushort* __restrict__ out, int n) {
  int i = (blockIdx.x * 256 + threadIdx.x) * 4;
  int stride = gridDim.x * 256 * 4;
  for (; i < n; i += stride) {
    float4 v = *(const float4*)(in + i);
    ushort4 o = { f2bf(v.x), f2bf(v.y), f2bf(v.z), f2bf(v.w) };
    *(ushort4*)(out + i) = o;
  }
}

// ---------------- transpose+convert: in[R][C] f32 -> out[C][R] bf16 ----------------
__global__ __launch_bounds__(256) void tcvt(const float* __restrict__ in,
                                            ushort* __restrict__ out, int R, int C) {
  __shared__ float tile[32][33];
  int c0 = blockIdx.x * 32, r0 = blockIdx.y * 32;
  int tx = threadIdx.x, ty = threadIdx.y;  // (32, 8)
  #pragma unroll
  for (int i = 0; i < 32; i += 8) tile[ty + i][tx] = in[(size_t)(r0 + ty + i) * C + c0 + tx];
  __syncthreads();
  #pragma unroll
  for (int i = 0; i < 32; i += 8) out[(size_t)(c0 + ty + i) * R + r0 + tx] = f2bf(tile[tx][ty + i]);
}

// ---------------- bf16 transpose: in [32][2048][64] -> out [32][64][2048] ----------------
__global__ __launch_bounds__(256) void vtrans(const ushort* __restrict__ in,
                                              ushort* __restrict__ out) {
  __shared__ ushort tile[32][33];
  int t0 = blockIdx.x * 32, d0 = blockIdx.y * 32, bh = blockIdx.z;
  int tx = threadIdx.x, ty = threadIdx.y;  // (32, 8)
  const ushort* src = in + (size_t)bh * 2048 * 64;
  ushort* dst = out + (size_t)bh * 64 * 2048;
  #pragma unroll
  for (int i = 0; i < 32; i += 8) tile[ty + i][tx] = src[(size_t)(t0 + ty + i) * 64 + d0 + tx];
  __syncthreads();
  #pragma unroll
  for (int i = 0; i < 32; i += 8) dst[(size_t)(d0 + ty + i) * 2048 + t0 + tx] = tile[tx][ty + i];
}

// ---------------- bf16 GEMM (m97 structure): C[M,N] = A[M,K] * BT[N,K]^T ----------------
// EPI=0: scatter bf16 into q/k/v [bh][t][64] (contiguous).  EPI=1: f32 store.
template <int EPI>
__global__ __launch_bounds__(256) void gemm_bf16(const ushort* __restrict__ A,
                                                 const ushort* __restrict__ BT,
                                                 ushort* __restrict__ qo, ushort* __restrict__ ko,
                                                 ushort* __restrict__ vo, float* __restrict__ outf,
                                                 int M, int N, int K) {
  __shared__ ushort Als[128 * 32];
  __shared__ ushort Bls[128 * 32];
  const int tid = threadIdx.x;
  const int lane = tid & 63;
  const int w = tid >> 6;
  const int wr = w >> 1, wc = w & 1;
  const int fr = lane & 15, fq = lane >> 4;
  const int bm0 = blockIdx.y * 128, bn0 = blockIdx.x * 128;
  const int srow = lane >> 2;
  const int scol = (lane & 3) * 8;

  f32x4 acc[4][4];
  #pragma unroll
  for (int m = 0; m < 4; m++)
    #pragma unroll
    for (int n = 0; n < 4; n++) acc[m][n] = (f32x4){0.f, 0.f, 0.f, 0.f};

  for (int k0 = 0; k0 < K; k0 += 32) {
    __syncthreads();
    #pragma unroll
    for (int c = 0; c < 2; c++) {
      int chunk = w * 2 + c;
      int rr = chunk * 16 + srow;
      gload16(&A[(size_t)(bm0 + rr) * K + k0 + scol], &Als[chunk * 512]);
      gload16(&BT[(size_t)(bn0 + rr) * K + k0 + scol], &Bls[chunk * 512]);
    }
    __syncthreads();
    bf16x8 a[4], b[4];
    #pragma unroll
    for (int m = 0; m < 4; m++) a[m] = *(bf16x8*)&Als[(wr * 64 + m * 16 + fr) * 32 + fq * 8];
    #pragma unroll
    for (int n = 0; n < 4; n++) b[n] = *(bf16x8*)&Bls[(wc * 64 + n * 16 + fr) * 32 + fq * 8];
    __builtin_amdgcn_s_setprio(1);
    #pragma unroll
    for (int m = 0; m < 4; m++)
      #pragma unroll
      for (int n = 0; n < 4; n++)
        acc[m][n] = __builtin_amdgcn_mfma_f32_16x16x32_bf16(a[m], b[n], acc[m][n], 0, 0, 0);
    __builtin_amdgcn_s_setprio(0);
  }

  #pragma unroll
  for (int m = 0; m < 4; m++) {
    #pragma unroll
    for (int n = 0; n < 4; n++) {
      #pragma unroll
      for (int jj = 0; jj < 4; jj++) {
        int r = bm0 + wr * 64 + m * 16 + fq * 4 + jj;  // C row = 4*(lane>>4)+reg
        int c = bn0 + wc * 64 + n * 16 + fr;           // C col = lane&15
        float val = acc[m][n][jj];
        if (EPI == 0) {
          int which = c >> 10, h = (c >> 6) & 15, dd = c & 63;
          int b_ = r >> 11, t = r & 2047;
          size_t bh = (size_t)(b_ * 16 + h);
          ushort* dst = (which == 0) ? qo : (which == 1 ? ko : vo);
          dst[(bh * 2048 + t) * 64 + dd] = f2bf(val);
        } else {
          outf[(size_t)r * N + c] = val;
        }
      }
    }
  }
}

// ---------------- flash attention (causal), shared dbuf staging, KVBLK=64 ----------------
// grid 1024: bh = bx&31, qt = 31-(bx>>5) (long blocks first). 4 waves/block;
// wave w owns q-rows [w*16, w*16+16). Block stages K + V^T tile ONCE into
// double-buffered LDS via named-reg loads (t+1 prefetch in flight across the
// whole compute phase). ONE __syncthreads per tile.
__global__ __launch_bounds__(256) void attn_fwd(const ushort* __restrict__ qg,
                                                const ushort* __restrict__ kg,
                                                const ushort* __restrict__ vtg,
                                                ushort* __restrict__ y) {
  __shared__ ushort Kls[2][64 * 72];  // [kv][d] stride 72
  __shared__ ushort Vls[2][64 * 68];  // [d][kv] stride 68
  __shared__ ushort Pw[4][16 * 68];   // per-wave P

  const int qt = 31 - (int)(blockIdx.x >> 5);
  const int bh = blockIdx.x & 31;
  const int tid = threadIdx.x, lane = tid & 63, w = tid >> 6;
  const int fr = lane & 15, fq = lane >> 4;
  const size_t base = (size_t)bh * 2048 * 64;
  const int b_ = bh >> 4, h = bh & 15;
  ushort* P_ = Pw[w];

  // staging coords: thread covers rows sr and sr+32, 16B col chunk sc
  const int sr = tid >> 3;           // 0..31
  const int sc = (tid & 7) * 8;
  const ushort* kg_l = kg + base + (size_t)sr * 64 + sc;     // + t*4096 (+2048 for row+32)
  const ushort* vg_l = vtg + base + (size_t)sr * 2048 + sc;  // + t*64 (+32*2048 for row+32)

  // Q fragments direct from global
  bf16x8 qf0 = *(const bf16x8*)&qg[base + (size_t)(qt * 64 + w * 16 + fr) * 64 + fq * 8];
  bf16x8 qf1 = *(const bf16x8*)&qg[base + (size_t)(qt * 64 + w * 16 + fr) * 64 + 32 + fq * 8];

  f32x4 o0 = {0.f,0.f,0.f,0.f}, o1 = {0.f,0.f,0.f,0.f}, o2 = {0.f,0.f,0.f,0.f}, o3 = {0.f,0.f,0.f,0.f};
  float l0 = 0.f, l1 = 0.f, l2 = 0.f, l3 = 0.f;

  uint4 k0r, k1r, v0r, v1r;  // named regs -> cannot lower to scratch

#define LOADT(t)                                              \
  do {                                                        \
    const ushort* kp = kg_l + (size_t)(t) * 4096;             \
    k0r = *(const uint4*)(kp);                                \
    k1r = *(const uint4*)(kp + 2048);                         \
    const ushort* vp = vg_l + (size_t)(t) * 64;               \
    v0r = *(const uint4*)(vp);                                \
    v1r = *(const uint4*)(vp + 32 * 2048);                    \
  } while (0)

  const float C_EXP2 = 0.18033688011112042f;  // 0.125 * log2(e)
  const int rowlim = w * 16 + fq * 4;         // + j = this thread's q-row (in-tile)

  LOADT(0);
  for (int t = 0; t <= qt; ++t) {
    ushort* Kc = Kls[t & 1];
    ushort* Vc = Vls[t & 1];
    // stage tile t (compiler waits vmcnt only for these four regs)
    *(uint4*)&Kc[(size_t)sr * 72 + sc] = k0r;
    *(uint4*)&Kc[(size_t)(sr + 32) * 72 + sc] = k1r;
    *(uint4*)&Vc[(size_t)sr * 68 + sc] = v0r;
    *(uint4*)&Vc[(size_t)(sr + 32) * 68 + sc] = v1r;
    __syncthreads();  // the ONLY barrier: dbuf makes read-protection implicit

    if (t < qt) LOADT(t + 1);  // prefetch; in flight through all compute below

    // S = Q K^T  [16 x 64]
    f32x4 s0 = {0.f,0.f,0.f,0.f}, s1 = {0.f,0.f,0.f,0.f}, s2 = {0.f,0.f,0.f,0.f}, s3 = {0.f,0.f,0.f,0.f};
    __builtin_amdgcn_s_setprio(1);
    #pragma unroll
    for (int ks = 0; ks < 2; ks++) {
      bf16x8 aq = ks ? qf1 : qf0;
      s0 = __builtin_amdgcn_mfma_f32_16x16x32_bf16(aq, *(bf16x8*)&Kc[( 0 + fr) * 72 + ks * 32 + fq * 8], s0, 0, 0, 0);
      s1 = __builtin_amdgcn_mfma_f32_16x16x32_bf16(aq, *(bf16x8*)&Kc[(16 + fr) * 72 + ks * 32 + fq * 8], s1, 0, 0, 0);
      s2 = __builtin_amdgcn_mfma_f32_16x16x32_bf16(aq, *(bf16x8*)&Kc[(32 + fr) * 72 + ks * 32 + fq * 8], s2, 0, 0, 0);
      s3 = __builtin_amdgcn_mfma_f32_16x16x32_bf16(aq, *(bf16x8*)&Kc[(48 + fr) * 72 + ks * 32 + fq * 8], s3, 0, 0, 0);
    }
    __builtin_amdgcn_s_setprio(0);

    // no-max softmax in exp2 domain; P -> per-wave LDS
    const bool diag = (t == qt);
    #pragma unroll
    for (int j = 0; j < 4; j++) {
      float v0 = s0[j] * C_EXP2, v1 = s1[j] * C_EXP2, v2 = s2[j] * C_EXP2, v3 = s3[j] * C_EXP2;
      if (diag) {
        int lim = rowlim + j;
        if ( 0 + fr > lim) v0 = -1e30f;
        if (16 + fr > lim) v1 = -1e30f;
        if (32 + fr > lim) v2 = -1e30f;
        if (48 + fr > lim) v3 = -1e30f;
      }
      float p0 = __builtin_amdgcn_exp2f(v0), p1 = __builtin_amdgcn_exp2f(v1);
      float p2 = __builtin_amdgcn_exp2f(v2), p3 = __builtin_amdgcn_exp2f(v3);
      float rs = (p0 + p1) + (p2 + p3);
      P_[(fq * 4 + j) * 68 +  0 + fr] = f2bf(p0);
      P_[(fq * 4 + j) * 68 + 16 + fr] = f2bf(p1);
      P_[(fq * 4 + j) * 68 + 32 + fr] = f2bf(p2);
      P_[(fq * 4 + j) * 68 + 48 + fr] = f2bf(p3);
      if (j == 0) l0 += rs; else if (j == 1) l1 += rs; else if (j == 2) l2 += rs; else l3 += rs;
    }

    // O += P V (P per-wave: in-order lgkmcnt RAW; V in current LDS buffer)
    __builtin_amdgcn_s_setprio(1);
    #pragma unroll
    for (int ks = 0; ks < 2; ks++) {
      bf16x8 pa = *(bf16x8*)&P_[fr * 68 + ks * 32 + fq * 8];
      o0 = __builtin_amdgcn_mfma_f32_16x16x32_bf16(pa, *(bf16x8*)&Vc[( 0 + fr) * 68 + ks * 32 + fq * 8], o0, 0, 0, 0);
      o1 = __builtin_amdgcn_mfma_f32_16x16x32_bf16(pa, *(bf16x8*)&Vc[(16 + fr) * 68 + ks * 32 + fq * 8], o1, 0, 0, 0);
      o2 = __builtin_amdgcn_mfma_f32_16x16x32_bf16(pa, *(bf16x8*)&Vc[(32 + fr) * 68 + ks * 32 + fq * 8], o2, 0, 0, 0);
      o3 = __builtin_amdgcn_mfma_f32_16x16x32_bf16(pa, *(bf16x8*)&Vc[(48 + fr) * 68 + ks * 32 + fq * 8], o3, 0, 0, 0);
    }
    __builtin_amdgcn_s_setprio(0);
  }
#undef LOADT

  // cross-lane l reduction (sum is linear; done once)
  float l_[4] = {l0, l1, l2, l3};
  #pragma unroll
  for (int j = 0; j < 4; j++) {
    float rs = l_[j];
    rs += __shfl_xor(rs, 1);
    rs += __shfl_xor(rs, 2);
    rs += __shfl_xor(rs, 4);
    rs += __shfl_xor(rs, 8);
    l_[j] = rs;
  }

  f32x4 oo[4] = {o0, o1, o2, o3};
  #pragma unroll
  for (int n2 = 0; n2 < 4; n2++) {
    #pragma unroll
    for (int j = 0; j < 4; j++) {
      int qrow = qt * 64 + w * 16 + fq * 4 + j;
      int dcol = n2 * 16 + fr;
      y[((size_t)(b_ * 2048 + qrow)) * 1024 + h * 64 + dcol] = f2bf(oo[n2][j] / l_[j]);
    }
  }
}

extern "C" void kernel_launch(void* const* d_in, const int* in_sizes, int n_in,
                              void* d_out, int out_size, void* d_ws, size_t ws_size,
                              hipStream_t stream) {
  const float* x = (const float*)d_in[0];
  const float* wqkv = (const float*)d_in[1];
  const float* wproj = (const float*)d_in[2];
  float* out = (float*)d_out;

  ushort* ws = (ushort*)d_ws;
  ushort* xb = ws;                               // 4096*1024
  ushort* wqkvT = xb + 4096 * 1024;              // 3072*1024  [N][K]
  ushort* wprojT = wqkvT + 3072 * 1024;          // 1024*1024  [N][K]
  ushort* qb = wprojT + 1024 * 1024;             // [bh][t][64]
  ushort* kb = qb + 32 * 2048 * 64;              // [bh][t][64]
  ushort* vb = kb + 32 * 2048 * 64;              // [bh][t][64]
  ushort* vtb = vb + 32 * 2048 * 64;             // [bh][64][t]
  ushort* yb = vtb + 32 * 2048 * 64;             // [B,T,1024]

  cvt_f32_bf16<<<1024, 256, 0, stream>>>(x, xb, 4096 * 1024);
  tcvt<<<dim3(96, 32), dim3(32, 8), 0, stream>>>(wqkv, wqkvT, 1024, 3072);
  tcvt<<<dim3(32, 32), dim3(32, 8), 0, stream>>>(wproj, wprojT, 1024, 1024);

  gemm_bf16<0><<<dim3(24, 32), 256, 0, stream>>>(xb, wqkvT, qb, kb, vb, nullptr, 4096, 3072, 1024);
  vtrans<<<dim3(64, 2, 32), dim3(32, 8), 0, stream>>>(vb, vtb);
  attn_fwd<<<1024, 256, 0, stream>>>(qb, kb, vtb, yb);
  gemm_bf16<1><<<dim3(8, 32), 256, 0, stream>>>(yb, wprojT, nullptr, nullptr, nullptr, out, 4096, 1024, 1024);
}

// Round 9
// 155.899 us; speedup vs baseline: 1.4471x; 1.2254x over previous
//
#include <hip/hip_runtime.h>
#include <hip/hip_bf16.h>

// B=2, T=2048, D=1024, H=16, dh=64. f32 in/out, bf16 MFMA internally.
// R9: split-KV attention (flash-decoding style). No-max softmax => partials
// combine by PURE SUMS. Block=(bh,qt,chunk of 4x128 kv), depth<=4 (was 16).
// nch==1 blocks write y directly; others write bf16 partial-O + f32 partial-l;
// combine kernel sums+divides. Inner loop: KVBLK=128, named-reg prefetch.

typedef __attribute__((ext_vector_type(8))) short bf16x8;
typedef __attribute__((ext_vector_type(4))) float f32x4;

__device__ __forceinline__ ushort f2bf(float f) {
  unsigned u = __builtin_bit_cast(unsigned, f);
  unsigned r = (u + 0x7fffu + ((u >> 16) & 1u)) >> 16;   // RNE
  return (ushort)r;
}
__device__ __forceinline__ float bf2f(ushort u) {
  unsigned v = ((unsigned)u) << 16;
  return __builtin_bit_cast(float, v);
}

__device__ __forceinline__ void gload16(const ushort* g, ushort* l) {
  auto gp = (const __attribute__((address_space(1))) void*)g;
  auto lp = (__attribute__((address_space(3))) void*)l;
  __builtin_amdgcn_global_load_lds(gp, lp, 16, 0, 0);
}

// ---------------- convert x: f32 -> bf16 ----------------
__global__ __launch_bounds__(256) void cvt_f32_bf16(const float* __restrict__ in,
                                                    ushort* __restrict__ out, int n) {
  int i = (blockIdx.x * 256 + threadIdx.x) * 4;
  int stride = gridDim.x * 256 * 4;
  for (; i < n; i += stride) {
    float4 v = *(const float4*)(in + i);
    ushort4 o = { f2bf(v.x), f2bf(v.y), f2bf(v.z), f2bf(v.w) };
    *(ushort4*)(out + i) = o;
  }
}

// ---------------- transpose+convert: in[R][C] f32 -> out[C][R] bf16 ----------------
__global__ __launch_bounds__(256) void tcvt(const float* __restrict__ in,
                                            ushort* __restrict__ out, int R, int C) {
  __shared__ float tile[32][33];
  int c0 = blockIdx.x * 32, r0 = blockIdx.y * 32;
  int tx = threadIdx.x, ty = threadIdx.y;  // (32, 8)
  #pragma unroll
  for (int i = 0; i < 32; i += 8) tile[ty + i][tx] = in[(size_t)(r0 + ty + i) * C + c0 + tx];
  __syncthreads();
  #pragma unroll
  for (int i = 0; i < 32; i += 8) out[(size_t)(c0 + ty + i) * R + r0 + tx] = f2bf(tile[tx][ty + i]);
}

// ---------------- bf16 transpose: in [32][2048][64] -> out [32][64][2048] ----------------
__global__ __launch_bounds__(256) void vtrans(const ushort* __restrict__ in,
                                              ushort* __restrict__ out) {
  __shared__ ushort tile[32][33];
  int t0 = blockIdx.x * 32, d0 = blockIdx.y * 32, bh = blockIdx.z;
  int tx = threadIdx.x, ty = threadIdx.y;  // (32, 8)
  const ushort* src = in + (size_t)bh * 2048 * 64;
  ushort* dst = out + (size_t)bh * 64 * 2048;
  #pragma unroll
  for (int i = 0; i < 32; i += 8) tile[ty + i][tx] = src[(size_t)(t0 + ty + i) * 64 + d0 + tx];
  __syncthreads();
  #pragma unroll
  for (int i = 0; i < 32; i += 8) dst[(size_t)(d0 + ty + i) * 2048 + t0 + tx] = tile[tx][ty + i];
}

// ---------------- bf16 GEMM (m97 structure): C[M,N] = A[M,K] * BT[N,K]^T ----------------
template <int EPI>
__global__ __launch_bounds__(256) void gemm_bf16(const ushort* __restrict__ A,
                                                 const ushort* __restrict__ BT,
                                                 ushort* __restrict__ qo, ushort* __restrict__ ko,
                                                 ushort* __restrict__ vo, float* __restrict__ outf,
                                                 int M, int N, int K) {
  __shared__ ushort Als[128 * 32];
  __shared__ ushort Bls[128 * 32];
  const int tid = threadIdx.x;
  const int lane = tid & 63;
  const int w = tid >> 6;
  const int wr = w >> 1, wc = w & 1;
  const int fr = lane & 15, fq = lane >> 4;
  const int bm0 = blockIdx.y * 128, bn0 = blockIdx.x * 128;
  const int srow = lane >> 2;
  const int scol = (lane & 3) * 8;

  f32x4 acc[4][4];
  #pragma unroll
  for (int m = 0; m < 4; m++)
    #pragma unroll
    for (int n = 0; n < 4; n++) acc[m][n] = (f32x4){0.f, 0.f, 0.f, 0.f};

  for (int k0 = 0; k0 < K; k0 += 32) {
    __syncthreads();
    #pragma unroll
    for (int c = 0; c < 2; c++) {
      int chunk = w * 2 + c;
      int rr = chunk * 16 + srow;
      gload16(&A[(size_t)(bm0 + rr) * K + k0 + scol], &Als[chunk * 512]);
      gload16(&BT[(size_t)(bn0 + rr) * K + k0 + scol], &Bls[chunk * 512]);
    }
    __syncthreads();
    bf16x8 a[4], b[4];
    #pragma unroll
    for (int m = 0; m < 4; m++) a[m] = *(bf16x8*)&Als[(wr * 64 + m * 16 + fr) * 32 + fq * 8];
    #pragma unroll
    for (int n = 0; n < 4; n++) b[n] = *(bf16x8*)&Bls[(wc * 64 + n * 16 + fr) * 32 + fq * 8];
    __builtin_amdgcn_s_setprio(1);
    #pragma unroll
    for (int m = 0; m < 4; m++)
      #pragma unroll
      for (int n = 0; n < 4; n++)
        acc[m][n] = __builtin_amdgcn_mfma_f32_16x16x32_bf16(a[m], b[n], acc[m][n], 0, 0, 0);
    __builtin_amdgcn_s_setprio(0);
  }

  #pragma unroll
  for (int m = 0; m < 4; m++) {
    #pragma unroll
    for (int n = 0; n < 4; n++) {
      #pragma unroll
      for (int jj = 0; jj < 4; jj++) {
        int r = bm0 + wr * 64 + m * 16 + fq * 4 + jj;
        int c = bn0 + wc * 64 + n * 16 + fr;
        float val = acc[m][n][jj];
        if (EPI == 0) {
          int which = c >> 10, h = (c >> 6) & 15, dd = c & 63;
          int b_ = r >> 11, t = r & 2047;
          size_t bh = (size_t)(b_ * 16 + h);
          ushort* dst = (which == 0) ? qo : (which == 1 ? ko : vo);
          dst[(bh * 2048 + t) * 64 + dd] = f2bf(val);
        } else {
          outf[(size_t)r * N + c] = val;
        }
      }
    }
  }
}

// ---------------- split-KV flash attention (causal), KVBLK=128, chunks of 4 tiles ----------
// grid 2560: bh = bx&31, i = bx>>5 -> (qt desc, chunk). 4 waves; wave w owns q-rows
// [w*16,w*16+16). Partials (bf16 O, f32 l) for nch>=2; direct y for nch==1.
__global__ __launch_bounds__(256, 3) void attn_fwd(const ushort* __restrict__ qg,
                                                   const ushort* __restrict__ kg,
                                                   const ushort* __restrict__ vtg,
                                                   ushort* __restrict__ y,
                                                   ushort* __restrict__ pO,
                                                   float* __restrict__ pl) {
  __shared__ ushort Ks[128 * 72];      // [kv][d]
  __shared__ ushort Vt[64 * 132];      // [d][kv]
  __shared__ ushort Ps[4][16 * 132];   // per-wave P

  const int bh = blockIdx.x & 31;
  const int i = blockIdx.x >> 5;       // 0..79, qt descending
  int acc = 0, qt = 31, nch = 4;
  for (int q = 31; q >= 0; --q) {
    int kk = (q >> 1) + 1;
    int nc = (kk + 3) >> 2;
    if (i < acc + nc) { qt = q; nch = nc; break; }
    acc += nc;
  }
  const int ch = i - acc;
  const int k = (qt >> 1) + 1;               // total 128-kv tiles for this qt
  const int t0 = ch * 4;
  const int t1 = (t0 + 4 < k) ? t0 + 4 : k;

  const int tid = threadIdx.x, lane = tid & 63, w = tid >> 6;
  const int fr = lane & 15, fq = lane >> 4;
  const size_t base = (size_t)bh * 2048 * 64;
  const int b_ = bh >> 4, h = bh & 15;
  ushort* P_ = Ps[w];

  // staging coords
  const int sr = tid >> 3;          // 0..31, K rows sr+32m
  const int sc = (tid & 7) * 8;
  const int vr = tid >> 4;          // 0..15, Vt rows vr+16m
  const int vc = (tid & 15) * 8;
  const ushort* kg_l = kg + base + (size_t)sr * 64 + sc;
  const ushort* vg_l = vtg + base + (size_t)vr * 2048 + vc;

  // Q fragments direct from global
  bf16x8 qf0 = *(const bf16x8*)&qg[base + (size_t)(qt * 64 + w * 16 + fr) * 64 + fq * 8];
  bf16x8 qf1 = *(const bf16x8*)&qg[base + (size_t)(qt * 64 + w * 16 + fr) * 64 + 32 + fq * 8];

  f32x4 o[4];
  #pragma unroll
  for (int n = 0; n < 4; n++) o[n] = (f32x4){0.f, 0.f, 0.f, 0.f};
  float l_[4] = {0.f, 0.f, 0.f, 0.f};

  uint4 k0r, k1r, k2r, k3r, v0r, v1r, v2r, v3r;  // named: cannot lower to scratch

#define LOADT(t)                                                   \
  do {                                                             \
    const ushort* kp = kg_l + (size_t)(t) * 8192;                  \
    k0r = *(const uint4*)(kp);         k1r = *(const uint4*)(kp + 2048); \
    k2r = *(const uint4*)(kp + 4096);  k3r = *(const uint4*)(kp + 6144); \
    const ushort* vp = vg_l + (size_t)(t) * 128;                   \
    v0r = *(const uint4*)(vp);              v1r = *(const uint4*)(vp + 16 * 2048); \
    v2r = *(const uint4*)(vp + 32 * 2048);  v3r = *(const uint4*)(vp + 48 * 2048); \
  } while (0)

  const float C_EXP2 = 0.18033688011112042f;  // 0.125 * log2(e)

  LOADT(t0);
  for (int t = t0; t < t1; ++t) {
    const int kv0 = t * 128;
    if (t > t0) __syncthreads();   // prev iter LDS reads done
    *(uint4*)&Ks[(size_t)sr * 72 + sc] = k0r;
    *(uint4*)&Ks[(size_t)(sr + 32) * 72 + sc] = k1r;
    *(uint4*)&Ks[(size_t)(sr + 64) * 72 + sc] = k2r;
    *(uint4*)&Ks[(size_t)(sr + 96) * 72 + sc] = k3r;
    *(uint4*)&Vt[(size_t)vr * 132 + vc] = v0r;
    *(uint4*)&Vt[(size_t)(vr + 16) * 132 + vc] = v1r;
    *(uint4*)&Vt[(size_t)(vr + 32) * 132 + vc] = v2r;
    *(uint4*)&Vt[(size_t)(vr + 48) * 132 + vc] = v3r;
    __syncthreads();               // staged

    if (t + 1 < t1) LOADT(t + 1);  // prefetch in flight across compute

    // S = Q K^T : [16 q] x [128 kv]
    f32x4 s[8];
    #pragma unroll
    for (int n = 0; n < 8; n++) s[n] = (f32x4){0.f, 0.f, 0.f, 0.f};
    __builtin_amdgcn_s_setprio(1);
    #pragma unroll
    for (int ks = 0; ks < 2; ks++) {
      bf16x8 aq = ks ? qf1 : qf0;
      #pragma unroll
      for (int n = 0; n < 8; n++) {
        bf16x8 bk = *(bf16x8*)&Ks[(n * 16 + fr) * 72 + ks * 32 + fq * 8];
        s[n] = __builtin_amdgcn_mfma_f32_16x16x32_bf16(aq, bk, s[n], 0, 0, 0);
      }
    }
    __builtin_amdgcn_s_setprio(0);

    // no-max softmax in exp2 domain
    const bool lastT = (t == k - 1);
    #pragma unroll
    for (int j = 0; j < 4; j++) {
      const int qrow = qt * 64 + w * 16 + fq * 4 + j;
      float rs = 0.f;
      #pragma unroll
      for (int n = 0; n < 8; n++) {
        float val = s[n][j] * C_EXP2;
        if (lastT && (kv0 + n * 16 + fr > qrow)) val = -1e30f;
        float p = __builtin_amdgcn_exp2f(val);
        rs += p;
        P_[(fq * 4 + j) * 132 + n * 16 + fr] = f2bf(p);
      }
      l_[j] += rs;
    }

    // O += P V
    __builtin_amdgcn_s_setprio(1);
    #pragma unroll
    for (int ks = 0; ks < 4; ks++) {
      bf16x8 pa = *(bf16x8*)&P_[fr * 132 + ks * 32 + fq * 8];
      #pragma unroll
      for (int n2 = 0; n2 < 4; n2++) {
        bf16x8 vb8 = *(bf16x8*)&Vt[(n2 * 16 + fr) * 132 + ks * 32 + fq * 8];
        o[n2] = __builtin_amdgcn_mfma_f32_16x16x32_bf16(pa, vb8, o[n2], 0, 0, 0);
      }
    }
    __builtin_amdgcn_s_setprio(0);
  }
#undef LOADT

  // cross-lane l reduction (over fr within fq group)
  #pragma unroll
  for (int j = 0; j < 4; j++) {
    float rs = l_[j];
    rs += __shfl_xor(rs, 1);
    rs += __shfl_xor(rs, 2);
    rs += __shfl_xor(rs, 4);
    rs += __shfl_xor(rs, 8);
    l_[j] = rs;
  }

  if (nch == 1) {
    #pragma unroll
    for (int n2 = 0; n2 < 4; n2++)
      #pragma unroll
      for (int j = 0; j < 4; j++) {
        int qrow = qt * 64 + w * 16 + fq * 4 + j;
        y[((size_t)(b_ * 2048 + qrow)) * 1024 + h * 64 + n2 * 16 + fr] = f2bf(o[n2][j] / l_[j]);
      }
  } else {
    const size_t ob = ((size_t)ch * 32 + bh) * 2048 * 64;
    #pragma unroll
    for (int n2 = 0; n2 < 4; n2++)
      #pragma unroll
      for (int j = 0; j < 4; j++) {
        int qrow = qt * 64 + w * 16 + fq * 4 + j;
        pO[ob + (size_t)qrow * 64 + n2 * 16 + fr] = f2bf(o[n2][j]);
      }
    if (fr == 0) {
      #pragma unroll
      for (int j = 0; j < 4; j++)
        pl[((size_t)ch * 32 + bh) * 2048 + qt * 64 + w * 16 + fq * 4 + j] = l_[j];
    }
  }
}

// ---------------- combine partials: y = (sum_c O_c) / (sum_c l_c) ----------------
__global__ __launch_bounds__(256) void attn_combine(const ushort* __restrict__ pO,
                                                    const float* __restrict__ pl,
                                                    ushort* __restrict__ y) {
  const int total = 32 * 2048 * 64;
  for (int flat = blockIdx.x * 256 + threadIdx.x; flat < total; flat += gridDim.x * 256) {
    int d = flat & 63;
    int t = (flat >> 6) & 2047;
    int bh = flat >> 17;
    int qt = t >> 6;
    int k = (qt >> 1) + 1;
    int nch = (k + 3) >> 2;
    if (nch < 2) continue;  // written directly by attn_fwd
    float os = 0.f, ls = 0.f;
    for (int c = 0; c < nch; ++c) {
      os += bf2f(pO[((size_t)c * 32 + bh) * 2048 * 64 + (size_t)t * 64 + d]);
      ls += pl[((size_t)c * 32 + bh) * 2048 + t];
    }
    int b_ = bh >> 4, h = bh & 15;
    y[((size_t)(b_ * 2048 + t)) * 1024 + h * 64 + d] = f2bf(os / ls);
  }
}

extern "C" void kernel_launch(void* const* d_in, const int* in_sizes, int n_in,
                              void* d_out, int out_size, void* d_ws, size_t ws_size,
                              hipStream_t stream) {
  const float* x = (const float*)d_in[0];
  const float* wqkv = (const float*)d_in[1];
  const float* wproj = (const float*)d_in[2];
  float* out = (float*)d_out;

  ushort* ws = (ushort*)d_ws;
  ushort* xb = ws;                               // 4096*1024
  ushort* wqkvT = xb + 4096 * 1024;              // 3072*1024  [N][K]
  ushort* wprojT = wqkvT + 3072 * 1024;          // 1024*1024  [N][K]
  ushort* qb = wprojT + 1024 * 1024;             // [bh][t][64]
  ushort* kb = qb + 32 * 2048 * 64;              // [bh][t][64]
  ushort* vb = kb + 32 * 2048 * 64;              // [bh][t][64]
  ushort* vtb = vb + 32 * 2048 * 64;             // [bh][64][t]
  ushort* yb = vtb + 32 * 2048 * 64;             // [B,T,1024]
  ushort* pO = yb + 4096 * 1024;                 // [4][32][2048][64] bf16 partial O
  float*  pl = (float*)(pO + (size_t)4 * 32 * 2048 * 64);  // [4][32][2048] f32

  cvt_f32_bf16<<<1024, 256, 0, stream>>>(x, xb, 4096 * 1024);
  tcvt<<<dim3(96, 32), dim3(32, 8), 0, stream>>>(wqkv, wqkvT, 1024, 3072);
  tcvt<<<dim3(32, 32), dim3(32, 8), 0, stream>>>(wproj, wprojT, 1024, 1024);

  gemm_bf16<0><<<dim3(24, 32), 256, 0, stream>>>(xb, wqkvT, qb, kb, vb, nullptr, 4096, 3072, 1024);
  vtrans<<<dim3(64, 2, 32), dim3(32, 8), 0, stream>>>(vb, vtb);
  attn_fwd<<<2560, 256, 0, stream>>>(qb, kb, vtb, yb, pO, pl);
  attn_combine<<<2048, 256, 0, stream>>>(pO, pl, yb);
  gemm_bf16<1><<<dim3(8, 32), 256, 0, stream>>>(yb, wprojT, nullptr, nullptr, nullptr, out, 4096, 1024, 1024);
}